// Round 20
// baseline (41207.089 us; speedup 1.0000x reference)
//
#include <hip/hip_runtime.h>
#include <math.h>

#define TT 256
#define BB 128
#define II 1024
#define HH 1536
#define H3 (3 * HH)
#define PANEL 512     // BLIS KC (proven R17)
#define CH 32         // steps per precomputed-Wx chunk
#define NCH (TT / CH) // 8

// FROZEN SEMANTICS (R17): per element, K in greedy 512-panels (x: p0,p1;
// y: P0,P1,P2), sequential f32 fmaf within panel, combine wx=(p0+p1),
// rh=((P0+P1)+P2), strict unfused f32 elementwise, cr-f32 transcendentals
// via f64, f32 state. R20: (a) input projection hoisted out of the serial
// path (precomputed per 32-step chunk, bit-identical p0+p1), (b) recurrent
// gemm at 8 waves/WG with weights read once per step.

__device__ float g_y[2][BB * HH];
__device__ float g_h[BB * HH];
__device__ float g_tr[BB * HH];
__device__ float g_wx[CH][BB][H3];        // 75.5 MB, L3-resident
__device__ float g_part[3][3][BB][HH];    // 7 MB recurrent partials

__device__ __forceinline__ float cr_expf(float x) { return (float)exp((double)x); }
__device__ __forceinline__ float cr_tanhf(float x) { return (float)tanh((double)x); }

__global__ void egru_init(const float* __restrict__ h0,
                          float* __restrict__ y0, float* __restrict__ h0o,
                          float* __restrict__ o0, float* __restrict__ tr0) {
    int i = blockIdx.x * blockDim.x + threadIdx.x;
    if (i < BB * HH) {
        const float v = h0[i];
        g_y[0][i] = v;
        g_h[i] = 0.0f;
        g_tr[i] = 0.0f;
        y0[i] = v;
        h0o[i] = 0.0f;
        o0[i] = 0.0f;
        tr0[i] = 0.0f;
    }
}

// Precompute Wx for one 32-step chunk: wx = (p0 + p1), exact R17 chains.
// WG = one step-row-block (128 rows) x 16 j; 512 thr = 8 waves; thread = 4 rows.
// grid (96 strips, 32 steps) -> 3072 WGs. blockIdx%8 == strip%8 keeps a
// strip's weight lines on one XCD's L2 across its 32 row-blocks.
__global__ __launch_bounds__(512) void egru_wx(
    const float* __restrict__ xc,    // [CH*BB, II] chunk of input
    const float* __restrict__ Wk) {  // [II, H3]
    const int js = blockIdx.x;       // 0..95
    const int rb = blockIdx.y;       // 0..31 (step within chunk)
    const int lane = threadIdx.x & 63;
    const int wv = threadIdx.x >> 6;
    const int jl = lane & 15;
    const int rg = lane >> 4;
    const int j = js * 16 + jl;
    const int r0 = wv * 16 + rg * 4;     // batch row within step

    float p0[3][4], p1[3][4];
#pragma unroll
    for (int g = 0; g < 3; ++g)
#pragma unroll
        for (int rr = 0; rr < 4; ++rr) { p0[g][rr] = 0.f; p1[g][rr] = 0.f; }

    const float* __restrict__ xr = xc + ((size_t)rb * BB + r0) * II;

#pragma unroll 4
    for (int k = 0; k < PANEL; ++k) {
        const size_t wrow = (size_t)k * H3;
        const float w0 = Wk[wrow + j];
        const float w1 = Wk[wrow + HH + j];
        const float w2 = Wk[wrow + 2 * HH + j];
#pragma unroll
        for (int rr = 0; rr < 4; ++rr) {
            const float av = xr[(size_t)rr * II + k];
            p0[0][rr] = fmaf(av, w0, p0[0][rr]);
            p0[1][rr] = fmaf(av, w1, p0[1][rr]);
            p0[2][rr] = fmaf(av, w2, p0[2][rr]);
        }
    }
#pragma unroll 4
    for (int k = PANEL; k < II; ++k) {
        const size_t wrow = (size_t)k * H3;
        const float w0 = Wk[wrow + j];
        const float w1 = Wk[wrow + HH + j];
        const float w2 = Wk[wrow + 2 * HH + j];
#pragma unroll
        for (int rr = 0; rr < 4; ++rr) {
            const float av = xr[(size_t)rr * II + k];
            p1[0][rr] = fmaf(av, w0, p1[0][rr]);
            p1[1][rr] = fmaf(av, w1, p1[1][rr]);
            p1[2][rr] = fmaf(av, w2, p1[2][rr]);
        }
    }
#pragma unroll
    for (int rr = 0; rr < 4; ++rr) {
        g_wx[rb][r0 + rr][j]          = p0[0][rr] + p1[0][rr];  // exact R17 order
        g_wx[rb][r0 + rr][HH + j]     = p0[1][rr] + p1[1][rr];
        g_wx[rb][r0 + rr][2 * HH + j] = p0[2][rr] + p1[2][rr];
    }
}

// Recurrent panel gemm: WG = (strip, panel), 128 rows x 16 j, 512 thr = 8
// waves, thread = 4 rows x 3 gates. Weights read exactly once per step.
__global__ __launch_bounds__(512) void egru_rec(
    const float* __restrict__ Rk,    // [HH, H3]
    int sel) {
    const int js = blockIdx.x;       // 0..95
    const int pan = blockIdx.y;      // 0..2
    const int lane = threadIdx.x & 63;
    const int wv = threadIdx.x >> 6;
    const int jl = lane & 15;
    const int rg = lane >> 4;
    const int j = js * 16 + jl;
    const int r0 = wv * 16 + rg * 4;
    const float* __restrict__ yp = g_y[sel];
    const int k0 = pan * PANEL;

    float a[3][4];
#pragma unroll
    for (int g = 0; g < 3; ++g)
#pragma unroll
        for (int rr = 0; rr < 4; ++rr) a[g][rr] = 0.f;

#pragma unroll 4
    for (int k = k0; k < k0 + PANEL; ++k) {
        const size_t rrow = (size_t)k * H3;
        const float w0 = Rk[rrow + j];
        const float w1 = Rk[rrow + HH + j];
        const float w2 = Rk[rrow + 2 * HH + j];
#pragma unroll
        for (int rr = 0; rr < 4; ++rr) {
            const float yv = yp[(r0 + rr) * HH + k];
            a[0][rr] = fmaf(yv, w0, a[0][rr]);
            a[1][rr] = fmaf(yv, w1, a[1][rr]);
            a[2][rr] = fmaf(yv, w2, a[2][rr]);
        }
    }
#pragma unroll
    for (int rr = 0; rr < 4; ++rr) {
        g_part[pan][0][r0 + rr][j] = a[0][rr];
        g_part[pan][1][r0 + rr][j] = a[1][rr];
        g_part[pan][2][r0 + rr][j] = a[2][rr];
    }
}

// Ordered combine + frozen elementwise chain + state update + outputs.
__global__ __launch_bounds__(256) void egru_combine(
    const float* __restrict__ bias, const float* __restrict__ rbias,
    const float* __restrict__ thr, int sel, int slot,
    float* __restrict__ yo, float* __restrict__ ho,
    float* __restrict__ oo, float* __restrict__ tro) {
#pragma clang fp contract(off)
    const int i = blockIdx.x * 256 + threadIdx.x;   // 0..BB*HH-1
    const int row = i / HH;
    const int j = i - row * HH;
    float* __restrict__ yn = g_y[sel ^ 1];

    const float axz = g_wx[slot][row][j];
    const float axr = g_wx[slot][row][HH + j];
    const float axg = g_wx[slot][row][2 * HH + j];
    // exact R17 recurrent-panel order: (P0+P1)+P2
    const float ahz = (g_part[0][0][row][j] + g_part[1][0][row][j]) + g_part[2][0][row][j];
    const float ahr = (g_part[0][1][row][j] + g_part[1][1][row][j]) + g_part[2][1][row][j];
    const float ahg = (g_part[0][2][row][j] + g_part[1][2][row][j]) + g_part[2][2][row][j];

    const float th = thr[j];
    const float zx = axz + bias[j];
    const float rx = axr + bias[HH + j];
    const float gx = axg + bias[2 * HH + j];
    const float zh = ahz + rbias[j];
    const float rh = ahr + rbias[HH + j];
    const float gh = ahg + rbias[2 * HH + j];
    const float pz = zx + zh;
    const float ez = cr_expf(-pz);
    const float dz = 1.0f + ez;
    const float z = 1.0f / dz;
    const float pr = rx + rh;
    const float er = cr_expf(-pr);
    const float dr = 1.0f + er;
    const float r = 1.0f / dr;
    const float rgh = r * gh;
    const float pg = gx + rgh;
    const float g = cr_tanhf(pg);
    const float hp = g_h[i];
    const float t1 = z * hp;
    const float omz = 1.0f - z;
    const float t2 = omz * g;
    const float cur = t1 + t2;
    const float margin = cur - th;
    const float ev = (margin > 0.0f) ? 1.0f : 0.0f;
    const float evth = ev * th;
    const float nh = cur - evth;
    const float ny = ev * cur;
    const float ta = 0.9f * g_tr[i];
    const float tb = 0.1f * ny;
    const float ntr = ta + tb;
    g_h[i] = nh;
    g_tr[i] = ntr;
    yn[i] = ny;
    yo[i] = ny;
    ho[i] = nh;
    oo[i] = ev;
    tro[i] = ntr;
}

extern "C" void kernel_launch(void* const* d_in, const int* in_sizes, int n_in,
                              void* d_out, int out_size, void* d_ws, size_t ws_size,
                              hipStream_t stream) {
    // bind inputs by element count (validated: matches dict order)
    const long long EXP[7] = {33554432LL, 196608LL, 4718592LL, 7077888LL, 4608LL, 4608LL, 1536LL};
    const void* p[7];
    bool used[16] = {false};
    bool ok = (n_in >= 7);
    if (ok) {
        for (int s = 0; s < 7; ++s) {
            int found = -1;
            for (int i = 0; i < n_in && i < 16; ++i)
                if (!used[i] && (long long)in_sizes[i] == EXP[s]) { found = i; break; }
            if (found < 0) { ok = false; break; }
            used[found] = true;
            p[s] = d_in[found];
        }
    }
    if (!ok) for (int s = 0; s < 7; ++s) p[s] = d_in[s];

    const float* input = (const float*)p[0];
    const float* h0    = (const float*)p[1];
    const float* Wk    = (const float*)p[2];
    const float* Rk    = (const float*)p[3];
    const float* bias  = (const float*)p[4];
    const float* rbias = (const float*)p[5];
    const float* thr   = (const float*)p[6];

    float* out = (float*)d_out;
    const size_t plane = (size_t)BB * HH;
    const size_t seq = (size_t)out_size / 4;
    float* y = out;
    float* h = out + seq;
    float* o = out + 2 * seq;
    float* tr = out + 3 * seq;

    egru_init<<<dim3((unsigned)((plane + 255) / 256)), dim3(256), 0, stream>>>(
        h0, y, h, o, tr);

    for (int c = 0; c < NCH; ++c) {
        egru_wx<<<dim3(HH / 16, CH), dim3(512), 0, stream>>>(
            input + (size_t)c * CH * BB * II, Wk);
        for (int s = 0; s < CH; ++s) {
            const int t = c * CH + s;
            const int sel = t & 1;
            const size_t pl = (size_t)(t + 1) * plane;
            egru_rec<<<dim3(HH / 16, 3), dim3(512), 0, stream>>>(Rk, sel);
            egru_combine<<<dim3((unsigned)(plane / 256)), dim3(256), 0, stream>>>(
                bias, rbias, thr, sel, s,
                y + pl, h + pl, o + pl, tr + pl);
        }
    }
}

// Round 21
// 28754.889 us; speedup vs baseline: 1.4330x; 1.4330x over previous
//
#include <hip/hip_runtime.h>
#include <math.h>

#define TT 256
#define BB 128
#define II 1024
#define HH 1536
#define H3 (3 * HH)
#define PANEL 512     // BLIS KC (proven R17)
#define CH 32         // steps per precomputed-Wx chunk
#define NCH (TT / CH) // 8
#define RV 8          // rows per thread (serial register loop)

// FROZEN SEMANTICS (R17): per element, K in greedy 512-panels (x: p0,p1;
// y: P0,P1,P2), sequential f32 fmaf within panel, combine wx=(p0+p1),
// rh=((P0+P1)+P2), strict unfused f32 elementwise, cr-f32 transcendentals
// via f64, f32 state.
// R21: kill the TA line-request wall (R19/R20 post-mortem): wave = 64
// consecutive j (weights coalesced), rows via wave-uniform float4 loads
// (readfirstlane'd base -> 1-line broadcast), XCD-swizzled so each XCD's
// weight slice stays L2-resident.

__device__ __align__(16) float g_y[2][BB * HH];
__device__ float g_h[BB * HH];
__device__ float g_tr[BB * HH];
__device__ __align__(16) float g_wx[CH][BB][H3];     // 75.5 MB, L3-resident
__device__ float g_part[3][3][BB][HH];               // 7 MB recurrent partials

__device__ __forceinline__ float cr_expf(float x) { return (float)exp((double)x); }
__device__ __forceinline__ float cr_tanhf(float x) { return (float)tanh((double)x); }

__global__ void egru_init(const float* __restrict__ h0,
                          float* __restrict__ y0, float* __restrict__ h0o,
                          float* __restrict__ o0, float* __restrict__ tr0) {
    int i = blockIdx.x * blockDim.x + threadIdx.x;
    if (i < BB * HH) {
        const float v = h0[i];
        g_y[0][i] = v;
        g_h[i] = 0.0f;
        g_tr[i] = 0.0f;
        y0[i] = v;
        h0o[i] = 0.0f;
        o0[i] = 0.0f;
        tr0[i] = 0.0f;
    }
}

// ---- Wx precompute: wx = (p0 + p1), exact R17 chains. ----
// WG 256 thr = 4 waves. wave = 64 consecutive j x 8 rows (serial in-thread).
// grid 3072 = 24 jb x 32 steps x 4 row-quads, XCD-swizzled: jb%8 == bid%8.
__global__ __launch_bounds__(256) void egru_wx(
    const float* __restrict__ xc,    // [CH*BB, II] chunk of input
    const float* __restrict__ Wk) {  // [II, H3]
    const int bid = blockIdx.x;
    const int w = bid >> 3;          // 0..383
    const int jbh = w / 128;         // 0..2
    const int rem = w - jbh * 128;
    const int step = rem >> 2;       // 0..31
    const int rq = rem & 3;
    const int jb = jbh * 8 + (bid & 7);
    const int lane = threadIdx.x & 63;
    const int wv = threadIdx.x >> 6;
    const int j = jb * 64 + lane;
    int r0 = (rq * 4 + wv) * RV;
    r0 = __builtin_amdgcn_readfirstlane(r0);
    const float* __restrict__ xbase = xc + ((size_t)step * BB + r0) * II;

    float p0[3][RV], p1[3][RV];
#pragma unroll
    for (int g = 0; g < 3; ++g)
#pragma unroll
        for (int rr = 0; rr < RV; ++rr) { p0[g][rr] = 0.f; p1[g][rr] = 0.f; }

#define WX_PANEL(ACC, K0, K1)                                                   \
    for (int k = (K0); k < (K1); k += 4) {                                      \
        float4 xv[RV];                                                          \
        _Pragma("unroll")                                                       \
        for (int rr = 0; rr < RV; ++rr)                                         \
            xv[rr] = *(const float4*)(xbase + (size_t)rr * II + k);             \
        _Pragma("unroll")                                                       \
        for (int kk = 0; kk < 4; ++kk) {                                        \
            const size_t wrow = (size_t)(k + kk) * H3;                          \
            const float w0 = Wk[wrow + j];                                      \
            const float w1 = Wk[wrow + HH + j];                                 \
            const float w2 = Wk[wrow + 2 * HH + j];                             \
            _Pragma("unroll")                                                   \
            for (int rr = 0; rr < RV; ++rr) {                                   \
                const float xvv = ((const float*)&xv[rr])[kk];                  \
                ACC[0][rr] = fmaf(xvv, w0, ACC[0][rr]);                         \
                ACC[1][rr] = fmaf(xvv, w1, ACC[1][rr]);                         \
                ACC[2][rr] = fmaf(xvv, w2, ACC[2][rr]);                         \
            }                                                                   \
        }                                                                       \
    }
    WX_PANEL(p0, 0, PANEL)
    WX_PANEL(p1, PANEL, II)
#undef WX_PANEL

#pragma unroll
    for (int rr = 0; rr < RV; ++rr) {
        g_wx[step][r0 + rr][j]          = p0[0][rr] + p1[0][rr];  // exact R17 order
        g_wx[step][r0 + rr][HH + j]     = p0[1][rr] + p1[1][rr];
        g_wx[step][r0 + rr][2 * HH + j] = p0[2][rr] + p1[2][rr];
    }
}

// ---- Recurrent panel gemm ----
// WG 256 thr = 4 waves; wave = 64 consecutive j x 8 rows. grid 288 =
// 72 (jb,panel) pairs x 4 row-quads, XCD-swizzled: pair%8 == bid%8 so each
// XCD's weight slice (9 pairs x 384KB = 3.5MB) is L2-resident across steps.
__global__ __launch_bounds__(256) void egru_rec(
    const float* __restrict__ Rk,    // [HH, H3]
    int sel) {
    const int bid = blockIdx.x;
    const int w = bid >> 3;          // 0..35
    const int phigh = w >> 2;        // 0..8
    const int rq = w & 3;
    const int p = phigh * 8 + (bid & 7);   // 0..71
    const int jb = p / 3;
    const int pan = p - jb * 3;
    const int lane = threadIdx.x & 63;
    const int wv = threadIdx.x >> 6;
    const int j = jb * 64 + lane;
    int r0 = (rq * 4 + wv) * RV;
    r0 = __builtin_amdgcn_readfirstlane(r0);
    const float* __restrict__ ybase = g_y[sel] + (size_t)r0 * HH;
    const int k0 = pan * PANEL;

    float a[3][RV];
#pragma unroll
    for (int g = 0; g < 3; ++g)
#pragma unroll
        for (int rr = 0; rr < RV; ++rr) a[g][rr] = 0.f;

    for (int k = k0; k < k0 + PANEL; k += 4) {
        float4 yv[RV];
#pragma unroll
        for (int rr = 0; rr < RV; ++rr)
            yv[rr] = *(const float4*)(ybase + (size_t)rr * HH + k);
#pragma unroll
        for (int kk = 0; kk < 4; ++kk) {
            const size_t rrow = (size_t)(k + kk) * H3;
            const float w0 = Rk[rrow + j];
            const float w1 = Rk[rrow + HH + j];
            const float w2 = Rk[rrow + 2 * HH + j];
#pragma unroll
            for (int rr = 0; rr < RV; ++rr) {
                const float yvv = ((const float*)&yv[rr])[kk];
                a[0][rr] = fmaf(yvv, w0, a[0][rr]);
                a[1][rr] = fmaf(yvv, w1, a[1][rr]);
                a[2][rr] = fmaf(yvv, w2, a[2][rr]);
            }
        }
    }
#pragma unroll
    for (int rr = 0; rr < RV; ++rr) {
        g_part[pan][0][r0 + rr][j] = a[0][rr];
        g_part[pan][1][r0 + rr][j] = a[1][rr];
        g_part[pan][2][r0 + rr][j] = a[2][rr];
    }
}

// ---- Ordered combine + frozen elementwise chain + state + outputs ----
__global__ __launch_bounds__(256) void egru_combine(
    const float* __restrict__ bias, const float* __restrict__ rbias,
    const float* __restrict__ thr, int sel, int slot,
    float* __restrict__ yo, float* __restrict__ ho,
    float* __restrict__ oo, float* __restrict__ tro) {
#pragma clang fp contract(off)
    const int i = blockIdx.x * 256 + threadIdx.x;   // 0..BB*HH-1
    const int row = i / HH;
    const int j = i - row * HH;
    float* __restrict__ yn = g_y[sel ^ 1];

    const float axz = g_wx[slot][row][j];
    const float axr = g_wx[slot][row][HH + j];
    const float axg = g_wx[slot][row][2 * HH + j];
    const float ahz = (g_part[0][0][row][j] + g_part[1][0][row][j]) + g_part[2][0][row][j];
    const float ahr = (g_part[0][1][row][j] + g_part[1][1][row][j]) + g_part[2][1][row][j];
    const float ahg = (g_part[0][2][row][j] + g_part[1][2][row][j]) + g_part[2][2][row][j];

    const float th = thr[j];
    const float zx = axz + bias[j];
    const float rx = axr + bias[HH + j];
    const float gx = axg + bias[2 * HH + j];
    const float zh = ahz + rbias[j];
    const float rh = ahr + rbias[HH + j];
    const float gh = ahg + rbias[2 * HH + j];
    const float pz = zx + zh;
    const float ez = cr_expf(-pz);
    const float dz = 1.0f + ez;
    const float z = 1.0f / dz;
    const float pr = rx + rh;
    const float er = cr_expf(-pr);
    const float dr = 1.0f + er;
    const float r = 1.0f / dr;
    const float rgh = r * gh;
    const float pg = gx + rgh;
    const float g = cr_tanhf(pg);
    const float hp = g_h[i];
    const float t1 = z * hp;
    const float omz = 1.0f - z;
    const float t2 = omz * g;
    const float cur = t1 + t2;
    const float margin = cur - th;
    const float ev = (margin > 0.0f) ? 1.0f : 0.0f;
    const float evth = ev * th;
    const float nh = cur - evth;
    const float ny = ev * cur;
    const float ta = 0.9f * g_tr[i];
    const float tb = 0.1f * ny;
    const float ntr = ta + tb;
    g_h[i] = nh;
    g_tr[i] = ntr;
    yn[i] = ny;
    yo[i] = ny;
    ho[i] = nh;
    oo[i] = ev;
    tro[i] = ntr;
}

extern "C" void kernel_launch(void* const* d_in, const int* in_sizes, int n_in,
                              void* d_out, int out_size, void* d_ws, size_t ws_size,
                              hipStream_t stream) {
    // bind inputs by element count (validated: matches dict order)
    const long long EXP[7] = {33554432LL, 196608LL, 4718592LL, 7077888LL, 4608LL, 4608LL, 1536LL};
    const void* p[7];
    bool used[16] = {false};
    bool ok = (n_in >= 7);
    if (ok) {
        for (int s = 0; s < 7; ++s) {
            int found = -1;
            for (int i = 0; i < n_in && i < 16; ++i)
                if (!used[i] && (long long)in_sizes[i] == EXP[s]) { found = i; break; }
            if (found < 0) { ok = false; break; }
            used[found] = true;
            p[s] = d_in[found];
        }
    }
    if (!ok) for (int s = 0; s < 7; ++s) p[s] = d_in[s];

    const float* input = (const float*)p[0];
    const float* h0    = (const float*)p[1];
    const float* Wk    = (const float*)p[2];
    const float* Rk    = (const float*)p[3];
    const float* bias  = (const float*)p[4];
    const float* rbias = (const float*)p[5];
    const float* thr   = (const float*)p[6];

    float* out = (float*)d_out;
    const size_t plane = (size_t)BB * HH;
    const size_t seq = (size_t)out_size / 4;
    float* y = out;
    float* h = out + seq;
    float* o = out + 2 * seq;
    float* tr = out + 3 * seq;

    egru_init<<<dim3((unsigned)((plane + 255) / 256)), dim3(256), 0, stream>>>(
        h0, y, h, o, tr);

    for (int c = 0; c < NCH; ++c) {
        egru_wx<<<dim3(3072), dim3(256), 0, stream>>>(
            input + (size_t)c * CH * BB * II, Wk);
        for (int s = 0; s < CH; ++s) {
            const int t = c * CH + s;
            const int sel = t & 1;
            const size_t pl = (size_t)(t + 1) * plane;
            egru_rec<<<dim3(288), dim3(256), 0, stream>>>(Rk, sel);
            egru_combine<<<dim3((unsigned)(plane / 256)), dim3(256), 0, stream>>>(
                bias, rbias, thr, sel, s,
                y + pl, h + pl, o + pl, tr + pl);
        }
    }
}

// Round 22
// 22359.599 us; speedup vs baseline: 1.8429x; 1.2860x over previous
//
#include <hip/hip_runtime.h>
#include <math.h>

#define TT 256
#define BB 128
#define II 1024
#define HH 1536
#define H3 (3 * HH)
#define PANEL 512     // BLIS KC (proven R17)
#define CH 32         // steps per precomputed-Wx chunk
#define NCH (TT / CH) // 8
#define RV 8          // rows per thread in wx kernel

// FROZEN SEMANTICS (R17): per element, K in greedy 512-panels (x: p0,p1;
// y: P0,P1,P2), sequential f32 fmaf within panel, combine wx=(p0+p1),
// rh=((P0+P1)+P2), strict unfused f32 elementwise, cr-f32 transcendentals
// via f64, f32 state.
// R22: rec latency attack -- 576 WGs (2.25 waves/SIMD), per-WG LDS staging
// of its 16-row y panel-slice (coalesced load, broadcast ds_read_b128 in the
// k-loop), unroll-2 k loop. Weight loads remain coalesced 64-dword bursts,
// XCD-pinned (jb,panel) pairs.

__device__ __align__(16) float g_y[2][BB * HH];
__device__ float g_h[BB * HH];
__device__ float g_tr[BB * HH];
__device__ __align__(16) float g_wx[CH][BB][H3];     // 75.5 MB, L3-resident
__device__ float g_part[3][3][BB][HH];               // 7 MB recurrent partials

__device__ __forceinline__ float cr_expf(float x) { return (float)exp((double)x); }
__device__ __forceinline__ float cr_tanhf(float x) { return (float)tanh((double)x); }

__global__ void egru_init(const float* __restrict__ h0,
                          float* __restrict__ y0, float* __restrict__ h0o,
                          float* __restrict__ o0, float* __restrict__ tr0) {
    int i = blockIdx.x * blockDim.x + threadIdx.x;
    if (i < BB * HH) {
        const float v = h0[i];
        g_y[0][i] = v;
        g_h[i] = 0.0f;
        g_tr[i] = 0.0f;
        y0[i] = v;
        h0o[i] = 0.0f;
        o0[i] = 0.0f;
        tr0[i] = 0.0f;
    }
}

// ---- Wx precompute (unchanged from R21): wx = (p0 + p1), exact R17 chains ----
__global__ __launch_bounds__(256) void egru_wx(
    const float* __restrict__ xc,    // [CH*BB, II] chunk of input
    const float* __restrict__ Wk) {  // [II, H3]
    const int bid = blockIdx.x;
    const int w = bid >> 3;          // 0..383
    const int jbh = w / 128;         // 0..2
    const int rem = w - jbh * 128;
    const int step = rem >> 2;       // 0..31
    const int rq = rem & 3;
    const int jb = jbh * 8 + (bid & 7);
    const int lane = threadIdx.x & 63;
    const int wv = threadIdx.x >> 6;
    const int j = jb * 64 + lane;
    int r0 = (rq * 4 + wv) * RV;
    r0 = __builtin_amdgcn_readfirstlane(r0);
    const float* __restrict__ xbase = xc + ((size_t)step * BB + r0) * II;

    float p0[3][RV], p1[3][RV];
#pragma unroll
    for (int g = 0; g < 3; ++g)
#pragma unroll
        for (int rr = 0; rr < RV; ++rr) { p0[g][rr] = 0.f; p1[g][rr] = 0.f; }

#define WX_PANEL(ACC, K0, K1)                                                   \
    for (int k = (K0); k < (K1); k += 4) {                                      \
        float4 xv[RV];                                                          \
        _Pragma("unroll")                                                       \
        for (int rr = 0; rr < RV; ++rr)                                         \
            xv[rr] = *(const float4*)(xbase + (size_t)rr * II + k);             \
        _Pragma("unroll")                                                       \
        for (int kk = 0; kk < 4; ++kk) {                                        \
            const size_t wrow = (size_t)(k + kk) * H3;                          \
            const float w0 = Wk[wrow + j];                                      \
            const float w1 = Wk[wrow + HH + j];                                 \
            const float w2 = Wk[wrow + 2 * HH + j];                             \
            _Pragma("unroll")                                                   \
            for (int rr = 0; rr < RV; ++rr) {                                   \
                const float xvv = ((const float*)&xv[rr])[kk];                  \
                ACC[0][rr] = fmaf(xvv, w0, ACC[0][rr]);                         \
                ACC[1][rr] = fmaf(xvv, w1, ACC[1][rr]);                         \
                ACC[2][rr] = fmaf(xvv, w2, ACC[2][rr]);                         \
            }                                                                   \
        }                                                                       \
    }
    WX_PANEL(p0, 0, PANEL)
    WX_PANEL(p1, PANEL, II)
#undef WX_PANEL

#pragma unroll
    for (int rr = 0; rr < RV; ++rr) {
        g_wx[step][r0 + rr][j]          = p0[0][rr] + p1[0][rr];  // exact R17 order
        g_wx[step][r0 + rr][HH + j]     = p0[1][rr] + p1[1][rr];
        g_wx[step][r0 + rr][2 * HH + j] = p0[2][rr] + p1[2][rr];
    }
}

// ---- Recurrent panel gemm (R22) ----
// grid 576 = 9 ph x 8 rq x 8 xcd; pair = ph*8+xcd (0..71) -> (jb,pan) pinned
// to one XCD. WG = 64 j x 16 rows x one 512-panel; 4 waves x 4 rows/wave.
// Stage: WG's 16 rows x 512 k of y into LDS (coalesced float4); k-loop reads
// broadcast ds_read_b128 + coalesced weight bursts.
__global__ __launch_bounds__(256) void egru_rec(
    const float* __restrict__ Rk,    // [HH, H3]
    int sel) {
    const int bid = blockIdx.x;
    const int xcd = bid & 7;
    const int w = bid >> 3;          // 0..71
    const int ph = w >> 3;           // 0..8
    const int rq = w & 7;            // 0..7
    const int pair = ph * 8 + xcd;   // 0..71
    const int jb = pair / 3;
    const int pan = pair - jb * 3;
    const int tid = threadIdx.x;
    const int lane = tid & 63;
    const int wv = tid >> 6;
    const int j = jb * 64 + lane;
    const int k0 = pan * PANEL;
    const int r0 = rq * 16;

    __shared__ __align__(16) float ylds[16][PANEL];   // 32 KB

    {   // coalesced stage: 16 rows x 128 float4 = 2048 float4, 8/thread
        const float* __restrict__ ysrc = g_y[sel];
#pragma unroll
        for (int it = 0; it < 8; ++it) {
            const int idx = it * 256 + tid;
            const int row = idx >> 7;
            const int c4 = idx & 127;
            const float4 v = *(const float4*)(ysrc + (size_t)(r0 + row) * HH + k0 + c4 * 4);
            *(float4*)&ylds[row][c4 * 4] = v;
        }
    }
    __syncthreads();

    const int rw = wv * 4;   // wave's first row (of its 4)

    float a[3][4];
#pragma unroll
    for (int g = 0; g < 3; ++g)
#pragma unroll
        for (int rr = 0; rr < 4; ++rr) a[g][rr] = 0.f;

#pragma unroll 2
    for (int k = 0; k < PANEL; k += 4) {
        float4 yv[4];
#pragma unroll
        for (int rr = 0; rr < 4; ++rr)
            yv[rr] = *(const float4*)&ylds[rw + rr][k];   // broadcast, conflict-free
#pragma unroll
        for (int kk = 0; kk < 4; ++kk) {
            const size_t rrow = (size_t)(k0 + k + kk) * H3;
            const float w0 = Rk[rrow + j];
            const float w1 = Rk[rrow + HH + j];
            const float w2 = Rk[rrow + 2 * HH + j];
#pragma unroll
            for (int rr = 0; rr < 4; ++rr) {
                const float yvv = ((const float*)&yv[rr])[kk];
                a[0][rr] = fmaf(yvv, w0, a[0][rr]);
                a[1][rr] = fmaf(yvv, w1, a[1][rr]);
                a[2][rr] = fmaf(yvv, w2, a[2][rr]);
            }
        }
    }
#pragma unroll
    for (int rr = 0; rr < 4; ++rr) {
        g_part[pan][0][r0 + rw + rr][j] = a[0][rr];
        g_part[pan][1][r0 + rw + rr][j] = a[1][rr];
        g_part[pan][2][r0 + rw + rr][j] = a[2][rr];
    }
}

// ---- Ordered combine + frozen elementwise chain + state + outputs ----
__global__ __launch_bounds__(256) void egru_combine(
    const float* __restrict__ bias, const float* __restrict__ rbias,
    const float* __restrict__ thr, int sel, int slot,
    float* __restrict__ yo, float* __restrict__ ho,
    float* __restrict__ oo, float* __restrict__ tro) {
#pragma clang fp contract(off)
    const int i = blockIdx.x * 256 + threadIdx.x;   // 0..BB*HH-1
    const int row = i / HH;
    const int j = i - row * HH;
    float* __restrict__ yn = g_y[sel ^ 1];

    const float axz = g_wx[slot][row][j];
    const float axr = g_wx[slot][row][HH + j];
    const float axg = g_wx[slot][row][2 * HH + j];
    const float ahz = (g_part[0][0][row][j] + g_part[1][0][row][j]) + g_part[2][0][row][j];
    const float ahr = (g_part[0][1][row][j] + g_part[1][1][row][j]) + g_part[2][1][row][j];
    const float ahg = (g_part[0][2][row][j] + g_part[1][2][row][j]) + g_part[2][2][row][j];

    const float th = thr[j];
    const float zx = axz + bias[j];
    const float rx = axr + bias[HH + j];
    const float gx = axg + bias[2 * HH + j];
    const float zh = ahz + rbias[j];
    const float rh = ahr + rbias[HH + j];
    const float gh = ahg + rbias[2 * HH + j];
    const float pz = zx + zh;
    const float ez = cr_expf(-pz);
    const float dz = 1.0f + ez;
    const float z = 1.0f / dz;
    const float pr = rx + rh;
    const float er = cr_expf(-pr);
    const float dr = 1.0f + er;
    const float r = 1.0f / dr;
    const float rgh = r * gh;
    const float pg = gx + rgh;
    const float g = cr_tanhf(pg);
    const float hp = g_h[i];
    const float t1 = z * hp;
    const float omz = 1.0f - z;
    const float t2 = omz * g;
    const float cur = t1 + t2;
    const float margin = cur - th;
    const float ev = (margin > 0.0f) ? 1.0f : 0.0f;
    const float evth = ev * th;
    const float nh = cur - evth;
    const float ny = ev * cur;
    const float ta = 0.9f * g_tr[i];
    const float tb = 0.1f * ny;
    const float ntr = ta + tb;
    g_h[i] = nh;
    g_tr[i] = ntr;
    yn[i] = ny;
    yo[i] = ny;
    ho[i] = nh;
    oo[i] = ev;
    tro[i] = ntr;
}

extern "C" void kernel_launch(void* const* d_in, const int* in_sizes, int n_in,
                              void* d_out, int out_size, void* d_ws, size_t ws_size,
                              hipStream_t stream) {
    // bind inputs by element count (validated: matches dict order)
    const long long EXP[7] = {33554432LL, 196608LL, 4718592LL, 7077888LL, 4608LL, 4608LL, 1536LL};
    const void* p[7];
    bool used[16] = {false};
    bool ok = (n_in >= 7);
    if (ok) {
        for (int s = 0; s < 7; ++s) {
            int found = -1;
            for (int i = 0; i < n_in && i < 16; ++i)
                if (!used[i] && (long long)in_sizes[i] == EXP[s]) { found = i; break; }
            if (found < 0) { ok = false; break; }
            used[found] = true;
            p[s] = d_in[found];
        }
    }
    if (!ok) for (int s = 0; s < 7; ++s) p[s] = d_in[s];

    const float* input = (const float*)p[0];
    const float* h0    = (const float*)p[1];
    const float* Wk    = (const float*)p[2];
    const float* Rk    = (const float*)p[3];
    const float* bias  = (const float*)p[4];
    const float* rbias = (const float*)p[5];
    const float* thr   = (const float*)p[6];

    float* out = (float*)d_out;
    const size_t plane = (size_t)BB * HH;
    const size_t seq = (size_t)out_size / 4;
    float* y = out;
    float* h = out + seq;
    float* o = out + 2 * seq;
    float* tr = out + 3 * seq;

    egru_init<<<dim3((unsigned)((plane + 255) / 256)), dim3(256), 0, stream>>>(
        h0, y, h, o, tr);

    for (int c = 0; c < NCH; ++c) {
        egru_wx<<<dim3(3072), dim3(256), 0, stream>>>(
            input + (size_t)c * CH * BB * II, Wk);
        for (int s = 0; s < CH; ++s) {
            const int t = c * CH + s;
            const int sel = t & 1;
            const size_t pl = (size_t)(t + 1) * plane;
            egru_rec<<<dim3(576), dim3(256), 0, stream>>>(Rk, sel);
            egru_combine<<<dim3((unsigned)(plane / 256)), dim3(256), 0, stream>>>(
                bias, rbias, thr, sel, s,
                y + pl, h + pl, o + pl, tr + pl);
        }
    }
}